// Round 6
// baseline (473.156 us; speedup 1.0000x reference)
//
#include <hip/hip_runtime.h>
#include <cstdint>
#include <cstddef>

// Fused LN + QKV + 4-token/2-head attention + out-proj + residual, MI355X.
// R8: weight-traffic amortization. ROWS=64 per block, two 32-row m-chunks
// share every B-fragment load (weight L2 bytes per row HALVED vs R7).
//  - chunk1's qkv parked in 48 acc VGPRs while chunk0 runs attention
//  - LDS exact 160 KiB: qkvf[32][768] f32 flat + xn hi/lo [64][256] bf16 flat
//  - XOR swizzles replace pad strides: xn 16B-granule ^= row&7; qkvf 4-word
//    granule ^= (row&7) ^ ((g4>>4)&3)<<1 (folds head/seg bits -> 8 bank groups)
//  - phases: P1(64) -> P2(both chunks) -> P3c0 -> [acc1 store + P4c0] -> P3c1
//    -> P4c1; 5 barriers per 64 rows (was 8)
//  - precision identical to R7 (A hi/lo pair, B single bf16, fp32 attention)

typedef __attribute__((ext_vector_type(8))) short short8;
typedef __attribute__((ext_vector_type(8))) unsigned short ushort8;
typedef __attribute__((ext_vector_type(16))) float floatx16;

#define DIM    256
#define HD     128
#define ROWS   64            // rows per block (2 chunks x 8 groups x 4 tokens)
#define NT32_QKV 24          // 768/32 n-tiles (32-wide)
#define NT32_OP  8           // 256/32 n-tiles
#define KS16     16          // 256/16 k-steps
#define SCALE  0.08838834764831845f   // 128^-0.5

// bf16 weights in 32x32x16 MFMA B-fragment order: [nt][ks][lane][8]
// B[k][col]: col = nt*32 + (lane&31), k = ks*16 + (lane>>5)*8 + j
__device__ unsigned short g_qkvw[NT32_QKV * KS16 * 64 * 8];   // 196608
__device__ unsigned short g_outw[NT32_OP * KS16 * 64 * 8];    //  65536

__device__ __forceinline__ unsigned short f2bf(float f) {
  unsigned int u = __builtin_bit_cast(unsigned int, f);
  u += 0x7fffu + ((u >> 16) & 1u);          // RNE
  return (unsigned short)(u >> 16);
}
__device__ __forceinline__ float bf2f(unsigned short h) {
  return __builtin_bit_cast(float, (unsigned int)h << 16);
}
// xn index: r = 0..63 (global), c = short col 0..255 (8-aligned use only)
__device__ __forceinline__ int xidx(int r, int c) {
  const int g = c >> 3;
  return r * 256 + (((g ^ (r & 7)) << 3) | (c & 7));
}
// qkvf index: r = 0..31 (chunk-local), w = word 0..767 (float4 use: w%4==0)
__device__ __forceinline__ int qidx(int r, int w) {
  const int g4 = w >> 2;
  const int g4s = g4 ^ ((r & 7) ^ (((g4 >> 4) & 3) << 1));
  return r * 768 + (g4s << 2) + (w & 3);
}

__global__ __launch_bounds__(256) void convert_weights(
    const float* __restrict__ qkv_w, const float* __restrict__ out_w) {
  const int id = blockIdx.x * 256 + threadIdx.x;   // 0..32767
  const float* src;
  unsigned short* dh;
  if (id < NT32_QKV * KS16 * 64) {                 // 24576 qkv fragment rows
    const int nt = id >> 10, ks = (id >> 6) & 15, lane = id & 63;
    src = qkv_w + (size_t)(nt * 32 + (lane & 31)) * DIM + ks * 16 + (lane >> 5) * 8;
    dh = g_qkvw + (size_t)id * 8;
  } else {
    const int id2 = id - NT32_QKV * KS16 * 64;     // 8192 out fragment rows
    const int nt = id2 >> 10, ks = (id2 >> 6) & 15, lane = id2 & 63;
    src = out_w + (size_t)(nt * 32 + (lane & 31)) * DIM + ks * 16 + (lane >> 5) * 8;
    dh = g_outw + (size_t)id2 * 8;
  }
  float4 a = *reinterpret_cast<const float4*>(src);
  float4 b = *reinterpret_cast<const float4*>(src + 4);
  ushort8 oh;
  oh[0] = f2bf(a.x); oh[1] = f2bf(a.y); oh[2] = f2bf(a.z); oh[3] = f2bf(a.w);
  oh[4] = f2bf(b.x); oh[5] = f2bf(b.y); oh[6] = f2bf(b.z); oh[7] = f2bf(b.w);
  *reinterpret_cast<ushort8*>(dh) = oh;
}

__global__ __launch_bounds__(512, 2) void fused_group_attn(
    const float* __restrict__ x,
    const float* __restrict__ qkv_b, const float* __restrict__ out_b,
    const float* __restrict__ ln_g, const float* __restrict__ ln_b,
    float* __restrict__ out) {
  __shared__ __align__(16) float qkvf[32 * 768];               // 98304 B
  __shared__ __align__(16) unsigned short xn_hi[ROWS * 256];   // 32768 B
  __shared__ __align__(16) unsigned short xn_lo[ROWS * 256];   // 32768 B

  const int tid  = threadIdx.x;
  const int lane = tid & 63;
  const int wid  = tid >> 6;          // 0..7
  const int l31  = lane & 31;
  const int khalf = lane >> 5;        // 0/1: k-subgroup for 32x32x16 A/B frags
  const size_t rowbase = (size_t)blockIdx.x * ROWS;

  // ---------- P1: load x, LayerNorm -> xn hi/lo (bf16 pair), 64 rows ----------
#pragma unroll
  for (int ch = 0; ch < 2; ++ch) {
    const int row = (tid >> 4);       // 0..31 (16 threads per row)
    const int xr  = ch * 32 + row;    // xn row 0..63
    const int seg = tid & 15;         // 16 cols each
    const float4* xr4 = reinterpret_cast<const float4*>(
        x + (rowbase + xr) * DIM + seg * 16);
    float4 v[4];
    float s = 0.f, sq = 0.f;
#pragma unroll
    for (int i = 0; i < 4; ++i) {
      v[i] = xr4[i];
      s  += v[i].x + v[i].y + v[i].z + v[i].w;
      sq += v[i].x * v[i].x + v[i].y * v[i].y + v[i].z * v[i].z + v[i].w * v[i].w;
    }
#pragma unroll
    for (int off = 1; off < 16; off <<= 1) {
      s  += __shfl_xor(s, off);
      sq += __shfl_xor(sq, off);
    }
    const float mu   = s * (1.f / DIM);
    const float var  = sq * (1.f / DIM) - mu * mu;
    const float rstd = rsqrtf(var + 1e-5f);
    const float4* g4 = reinterpret_cast<const float4*>(ln_g + seg * 16);
    const float4* b4 = reinterpret_cast<const float4*>(ln_b + seg * 16);
#pragma unroll
    for (int p = 0; p < 2; ++p) {
      float4 ga = g4[2 * p], gb = g4[2 * p + 1];
      float4 ba = b4[2 * p], bb = b4[2 * p + 1];
      float4 va = v[2 * p],  vb = v[2 * p + 1];
      float n[8] = {
        (va.x - mu) * rstd * ga.x + ba.x, (va.y - mu) * rstd * ga.y + ba.y,
        (va.z - mu) * rstd * ga.z + ba.z, (va.w - mu) * rstd * ga.w + ba.w,
        (vb.x - mu) * rstd * gb.x + bb.x, (vb.y - mu) * rstd * gb.y + bb.y,
        (vb.z - mu) * rstd * gb.z + bb.z, (vb.w - mu) * rstd * gb.w + bb.w};
      ushort8 oh, ol;
#pragma unroll
      for (int e = 0; e < 8; ++e) {
        unsigned short h = f2bf(n[e]);
        oh[e] = h;
        ol[e] = f2bf(n[e] - bf2f(h));
      }
      const int xo = xidx(xr, seg * 16 + p * 8);
      *reinterpret_cast<ushort8*>(&xn_hi[xo]) = oh;
      *reinterpret_cast<ushort8*>(&xn_lo[xo]) = ol;
    }
  }
  __syncthreads();

  // ---------- P2: QKV GEMM 32x32x16, both chunks share each B-load ----------
  floatx16 acc1[3];                   // chunk1 qkv parked in regs through P3c0
  {
    floatx16 acc0[3];
#pragma unroll
    for (int n = 0; n < 3; ++n)
#pragma unroll
      for (int i = 0; i < 16; ++i) { acc0[n][i] = 0.f; acc1[n][i] = 0.f; }
#pragma unroll
    for (int ks = 0; ks < KS16; ++ks) {
      const int xo0 = xidx(l31,      ks * 16 + khalf * 8);
      const int xo1 = xidx(32 + l31, ks * 16 + khalf * 8);
      short8 a0h = *reinterpret_cast<const short8*>(&xn_hi[xo0]);
      short8 a0l = *reinterpret_cast<const short8*>(&xn_lo[xo0]);
      short8 a1h = *reinterpret_cast<const short8*>(&xn_hi[xo1]);
      short8 a1l = *reinterpret_cast<const short8*>(&xn_lo[xo1]);
#pragma unroll
      for (int n = 0; n < 3; ++n) {
        const int boff = (((wid * 3 + n) * KS16 + ks) * 64 + lane) * 8;
        short8 bh = *reinterpret_cast<const short8*>(g_qkvw + boff);
        acc0[n] = __builtin_amdgcn_mfma_f32_32x32x16_bf16(a0h, bh, acc0[n], 0, 0, 0);
        acc0[n] = __builtin_amdgcn_mfma_f32_32x32x16_bf16(a0l, bh, acc0[n], 0, 0, 0);
        acc1[n] = __builtin_amdgcn_mfma_f32_32x32x16_bf16(a1h, bh, acc1[n], 0, 0, 0);
        acc1[n] = __builtin_amdgcn_mfma_f32_32x32x16_bf16(a1l, bh, acc1[n], 0, 0, 0);
      }
    }
    // stage chunk0 qkv -> LDS
#pragma unroll
    for (int n = 0; n < 3; ++n) {
      const int col = (wid * 3 + n) * 32 + l31;
      const float bias = qkv_b[col];
#pragma unroll
      for (int i = 0; i < 16; ++i) {
        const int row = (i & 3) + 8 * (i >> 2) + 4 * khalf;
        qkvf[qidx(row, col)] = acc0[n][i] + bias;
      }
    }
  }

  // P4 B-fragment prefetch (consumed by both P4 chunks; hidden under P3c0)
  short8 pb[KS16];
#pragma unroll
  for (int ks = 0; ks < KS16; ++ks)
    pb[ks] = *reinterpret_cast<const short8*>(
        g_outw + (size_t)((wid * KS16 + ks) * 64 + lane) * 8);

  __syncthreads();

  // ---------- P3 / P4 bodies (chunk-parameterized) ----------
  auto P3 = [&](int ch) {
    const int half = lane >> 5;       // head
    const int l5   = lane & 31;
    const int t = (l5 & 15) >> 2, u = l5 & 3, c = l5 >> 4;
    const int rq = 4 * wid + t;       // chunk-local qkvf rows
    const int rk = 4 * wid + u;
    float sdot = 0.f;
#pragma unroll
    for (int j = 0; j < 16; ++j) {
      const float4 qv = *reinterpret_cast<const float4*>(
          &qkvf[qidx(rq, half * HD + c * 64 + 4 * j)]);
      const float4 kv = *reinterpret_cast<const float4*>(
          &qkvf[qidx(rk, 256 + half * HD + c * 64 + 4 * j)]);
      sdot += qv.x * kv.x + qv.y * kv.y + qv.z * kv.z + qv.w * kv.w;
    }
    sdot += __shfl_xor(sdot, 16);     // combine the two 64-elem chunks
    sdot *= SCALE;
    float mx = fmaxf(sdot, __shfl_xor(sdot, 1));
    mx = fmaxf(mx, __shfl_xor(mx, 2));
    float ex = __expf(sdot - mx);
    float den = ex + __shfl_xor(ex, 1);
    den += __shfl_xor(den, 2);
    const float p = ex / den;         // P[t][u] replicated on c=0/1

    // PV: t2 = l5>>3, 16-col segment per lane
    const int t2 = l5 >> 3, dseg = l5 & 7;
    float o[16];
#pragma unroll
    for (int e = 0; e < 16; ++e) o[e] = 0.f;
#pragma unroll
    for (int uu = 0; uu < 4; ++uu) {
      const float pu = __shfl(p, (lane & 32) + t2 * 4 + uu);
      const int rv = 4 * wid + uu;
#pragma unroll
      for (int j = 0; j < 4; ++j) {
        const float4 vv = *reinterpret_cast<const float4*>(
            &qkvf[qidx(rv, 512 + half * HD + dseg * 16 + 4 * j)]);
        o[4 * j]     += pu * vv.x;
        o[4 * j + 1] += pu * vv.y;
        o[4 * j + 2] += pu * vv.z;
        o[4 * j + 3] += pu * vv.w;
      }
    }
    ushort8 h0, h1, l0, l1;
#pragma unroll
    for (int e = 0; e < 8; ++e) {
      unsigned short ha = f2bf(o[e]);
      h0[e] = ha; l0[e] = f2bf(o[e] - bf2f(ha));
      unsigned short hb = f2bf(o[e + 8]);
      h1[e] = hb; l1[e] = f2bf(o[e + 8] - bf2f(hb));
    }
    const int orow = ch * 32 + 4 * wid + t2;
    const int oc   = half * HD + dseg * 16;
    const int oo0 = xidx(orow, oc), oo1 = xidx(orow, oc + 8);
    *reinterpret_cast<ushort8*>(&xn_hi[oo0]) = h0;
    *reinterpret_cast<ushort8*>(&xn_hi[oo1]) = h1;
    *reinterpret_cast<ushort8*>(&xn_lo[oo0]) = l0;
    *reinterpret_cast<ushort8*>(&xn_lo[oo1]) = l1;
  };

  auto P4 = [&](int ch) {
    floatx16 acc;
#pragma unroll
    for (int i = 0; i < 16; ++i) acc[i] = 0.f;
#pragma unroll
    for (int ks = 0; ks < KS16; ++ks) {
      const int xo = xidx(ch * 32 + l31, ks * 16 + khalf * 8);
      short8 ah = *reinterpret_cast<const short8*>(&xn_hi[xo]);
      short8 al = *reinterpret_cast<const short8*>(&xn_lo[xo]);
      acc = __builtin_amdgcn_mfma_f32_32x32x16_bf16(ah, pb[ks], acc, 0, 0, 0);
      acc = __builtin_amdgcn_mfma_f32_32x32x16_bf16(al, pb[ks], acc, 0, 0, 0);
    }
    const int col = wid * 32 + l31;
    const float bias = out_b[col];
#pragma unroll
    for (int i = 0; i < 16; ++i) {
      const int row = (i & 3) + 8 * (i >> 2) + 4 * khalf;
      const size_t gidx = (rowbase + ch * 32 + row) * DIM + col;
      out[gidx] = acc[i] + bias + x[gidx];
    }
  };

  // ---------- chunk 0 attention ----------
  P3(0);
  __syncthreads();                    // qkvf c0 consumed; O0 visible

  // stage chunk1 qkv -> LDS, then out-proj chunk0 (overlaps the ds drain)
#pragma unroll
  for (int n = 0; n < 3; ++n) {
    const int col = (wid * 3 + n) * 32 + l31;
    const float bias = qkv_b[col];
#pragma unroll
    for (int i = 0; i < 16; ++i) {
      const int row = (i & 3) + 8 * (i >> 2) + 4 * khalf;
      qkvf[qidx(row, col)] = acc1[n][i] + bias;
    }
  }
  P4(0);
  __syncthreads();                    // qkvf c1 visible

  P3(1);
  __syncthreads();                    // O1 visible

  P4(1);
}

extern "C" void kernel_launch(void* const* d_in, const int* in_sizes, int n_in,
                              void* d_out, int out_size, void* d_ws, size_t ws_size,
                              hipStream_t stream) {
  const float* x     = (const float*)d_in[0];
  const float* qkv_w = (const float*)d_in[1];
  const float* qkv_b = (const float*)d_in[2];
  const float* out_w = (const float*)d_in[3];
  const float* out_b = (const float*)d_in[4];
  const float* ln_g  = (const float*)d_in[5];
  const float* ln_b  = (const float*)d_in[6];
  float* out = (float*)d_out;

  hipLaunchKernelGGL(convert_weights, dim3(128), dim3(256), 0, stream, qkv_w, out_w);

  const int rows = in_sizes[0] / DIM;     // 131072
  const int nblk = rows / ROWS;           // 2048
  hipLaunchKernelGGL(fused_group_attn, dim3(nblk), dim3(512), 0, stream,
                     x, qkv_b, out_b, ln_g, ln_b, out);
}